// Round 3
// baseline (403.378 us; speedup 1.0000x reference)
//
#include <hip/hip_runtime.h>

constexpr int TN     = 100000;
constexpr int CHUNKS = 1000;
constexpr int GROUPS = 100;
constexpr int CGRP   = 10;     // chunks per group; GROUPS*CGRP == CHUNKS

constexpr float LOG2E = 1.4426950408889634f;

// float offsets into ws (static region)
constexpr size_t OFF_W   = 0;      // 32x32
constexpr size_t OFF_W2  = 1024;   // 32x32
constexpr size_t OFF_I2V = 2048;   // 32  (i2v * LOG2E)
constexpr size_t OFF_LB  = 2112;   // 64  loss buckets
constexpr size_t OFF_XG  = 2176;   // GROUPS*32 group-start states
constexpr size_t OFF_QS  = 8192;   // SUB*1024 subchunk matrices, then qc/r/e0

// ---------------------------------------------------------------------------
// Prep (1 block, 256 thr): W[i][j] = aij*A_j*B_ij, W2 = W*A_j*B_ij, i2v*LOG2E
// ---------------------------------------------------------------------------
__global__ __launch_bounds__(256) void k_prep(
    const float* __restrict__ mean, const float* __restrict__ var,
    const float* __restrict__ bate_p, const float* __restrict__ aij,
    float* __restrict__ ws)
{
  const int tid = threadIdx.x;
  const int j = tid & 31, ig = tid >> 5;
  float vj   = var[j];
  float i2v  = 0.5f / vj;
  float norm = rsqrtf(2.0f * 3.1415926f * vj);
  float Aj   = norm * expf(mean[j] * i2v);
  float bate = bate_p[0];
  if (tid < 32) ws[OFF_I2V + tid] = i2v * LOG2E;
#pragma unroll
  for (int m = 0; m < 4; ++m) {
    int i = ig * 4 + m;
    float Bij = expf(-bate * mean[i] * i2v);
    float w = aij[i * 32 + j] * Aj * Bij;
    ws[OFF_W  + i * 32 + j] = w;
    ws[OFF_W2 + i * 32 + j] = w * Aj * Bij;
  }
}

// ---------------------------------------------------------------------------
// Phase 1: one wave per SUBCHUNK (slen steps). Lane (jt,it) owns a 4x4 tile,
// W columns in 128 VGPRs, Q double-buffered in LDS.
// Q_new[j,i] = u_j * sum_k W[k,j] * Q[k,i]
// ---------------------------------------------------------------------------
__global__ __launch_bounds__(64) void k_phase1(
    const float* __restrict__ obs2, const float* __restrict__ obs1,
    const float* __restrict__ bate_p, const float* __restrict__ ws,
    float* __restrict__ qs, int slen)
{
  const int b = blockIdx.x, lane = threadIdx.x;
  const int j0 = (lane >> 3) * 4, i0 = (lane & 7) * 4;
  __shared__ __align__(16) float Q[2][32][36];
  __shared__ float cts[100];

  const int t0 = b * slen;
  {
    float bate = bate_p[0];
    for (int l = lane; l < slen; l += 64)
      cts[l] = obs2[t0 + l] - bate * obs1[t0 + l];
  }
  float4 Wr[32];
  const float* Wg = ws + OFF_W;
#pragma unroll
  for (int k = 0; k < 32; ++k) Wr[k] = *(const float4*)&Wg[k * 32 + j0];
  float4 i2vl = *(const float4*)&ws[OFF_I2V + j0];

#pragma unroll
  for (int m = 0; m < 4; ++m) {
    float4 v;
    v.x = (j0 + m == i0 + 0) ? 1.0f : 0.0f;
    v.y = (j0 + m == i0 + 1) ? 1.0f : 0.0f;
    v.z = (j0 + m == i0 + 2) ? 1.0f : 0.0f;
    v.w = (j0 + m == i0 + 3) ? 1.0f : 0.0f;
    *(float4*)&Q[0][j0 + m][i0] = v;
  }
  __syncthreads();

  int buf = 0;
  for (int s = 0; s < slen; ++s) {
    float ct = cts[s];
    float4 a0 = {0,0,0,0}, a1 = {0,0,0,0}, a2 = {0,0,0,0}, a3 = {0,0,0,0};
#pragma unroll
    for (int k = 0; k < 32; ++k) {
      float4 q = *(const float4*)&Q[buf][k][i0];
      float4 w = Wr[k];
      a0.x += w.x * q.x; a0.y += w.x * q.y; a0.z += w.x * q.z; a0.w += w.x * q.w;
      a1.x += w.y * q.x; a1.y += w.y * q.y; a1.z += w.y * q.z; a1.w += w.y * q.w;
      a2.x += w.z * q.x; a2.y += w.z * q.y; a2.z += w.z * q.z; a2.w += w.z * q.w;
      a3.x += w.w * q.x; a3.y += w.w * q.y; a3.z += w.w * q.z; a3.w += w.w * q.w;
    }
    float u0 = exp2f(-ct * i2vl.x), u1 = exp2f(-ct * i2vl.y);
    float u2 = exp2f(-ct * i2vl.z), u3 = exp2f(-ct * i2vl.w);
    a0.x *= u0; a0.y *= u0; a0.z *= u0; a0.w *= u0;
    a1.x *= u1; a1.y *= u1; a1.z *= u1; a1.w *= u1;
    a2.x *= u2; a2.y *= u2; a2.z *= u2; a2.w *= u2;
    a3.x *= u3; a3.y *= u3; a3.z *= u3; a3.w *= u3;
    if (((s & 7) == 7) || s == slen - 1) {   // scale-invariant rescale
      float ps = a0.x + a0.y + a0.z + a0.w + a1.x + a1.y + a1.z + a1.w
               + a2.x + a2.y + a2.z + a2.w + a3.x + a3.y + a3.z + a3.w;
#pragma unroll
      for (int o = 1; o < 64; o <<= 1) ps += __shfl_xor(ps, o);
      float g = __builtin_amdgcn_rcpf(ps);
      a0.x *= g; a0.y *= g; a0.z *= g; a0.w *= g;
      a1.x *= g; a1.y *= g; a1.z *= g; a1.w *= g;
      a2.x *= g; a2.y *= g; a2.z *= g; a2.w *= g;
      a3.x *= g; a3.y *= g; a3.z *= g; a3.w *= g;
    }
    *(float4*)&Q[buf ^ 1][j0 + 0][i0] = a0;
    *(float4*)&Q[buf ^ 1][j0 + 1][i0] = a1;
    *(float4*)&Q[buf ^ 1][j0 + 2][i0] = a2;
    *(float4*)&Q[buf ^ 1][j0 + 3][i0] = a3;
    __syncthreads();
    buf ^= 1;
  }
  float* Qo = qs + (size_t)b * 1024;
#pragma unroll
  for (int m = 0; m < 4; ++m)
    *(float4*)&Qo[(j0 + m) * 32 + i0] = *(const float4*)&Q[buf][j0 + m][i0];
}

// ---------------------------------------------------------------------------
// comb0: chunk product from f consecutive subchunk matrices (1000 waves)
// R <- Qs[b*f]; R <- Qs[b*f+s] * R  (s = 1..f-1)
// ---------------------------------------------------------------------------
__global__ __launch_bounds__(64) void k_comb0(const float* __restrict__ qs,
                                              float* __restrict__ qc, int f)
{
  const int b = blockIdx.x, lane = threadIdx.x;
  const int j0 = (lane >> 3) * 4, i0 = (lane & 7) * 4;
  __shared__ __align__(16) float R[2][32][36];
  {
    const float* q0 = qs + (size_t)(b * f) * 1024;
#pragma unroll
    for (int m = 0; m < 4; ++m)
      *(float4*)&R[0][j0 + m][i0] = *(const float4*)&q0[(j0 + m) * 32 + i0];
  }
  __syncthreads();
  int buf = 0;
  for (int s = 1; s < f; ++s) {
    const float* ql = qs + (size_t)(b * f + s) * 1024;
    float Qv[4][32];
#pragma unroll
    for (int m = 0; m < 4; ++m)
#pragma unroll
      for (int kk = 0; kk < 8; ++kk) {
        float4 t = *(const float4*)&ql[(j0 + m) * 32 + kk * 4];
        Qv[m][kk * 4 + 0] = t.x; Qv[m][kk * 4 + 1] = t.y;
        Qv[m][kk * 4 + 2] = t.z; Qv[m][kk * 4 + 3] = t.w;
      }
    float4 a0 = {0,0,0,0}, a1 = {0,0,0,0}, a2 = {0,0,0,0}, a3 = {0,0,0,0};
#pragma unroll
    for (int k = 0; k < 32; ++k) {
      float4 r = *(const float4*)&R[buf][k][i0];
      a0.x += Qv[0][k] * r.x; a0.y += Qv[0][k] * r.y; a0.z += Qv[0][k] * r.z; a0.w += Qv[0][k] * r.w;
      a1.x += Qv[1][k] * r.x; a1.y += Qv[1][k] * r.y; a1.z += Qv[1][k] * r.z; a1.w += Qv[1][k] * r.w;
      a2.x += Qv[2][k] * r.x; a2.y += Qv[2][k] * r.y; a2.z += Qv[2][k] * r.z; a2.w += Qv[2][k] * r.w;
      a3.x += Qv[3][k] * r.x; a3.y += Qv[3][k] * r.y; a3.z += Qv[3][k] * r.z; a3.w += Qv[3][k] * r.w;
    }
    if (s == f - 1) {
      float ps = a0.x + a0.y + a0.z + a0.w + a1.x + a1.y + a1.z + a1.w
               + a2.x + a2.y + a2.z + a2.w + a3.x + a3.y + a3.z + a3.w;
#pragma unroll
      for (int o = 1; o < 64; o <<= 1) ps += __shfl_xor(ps, o);
      float gg = __builtin_amdgcn_rcpf(ps);
      a0.x *= gg; a0.y *= gg; a0.z *= gg; a0.w *= gg;
      a1.x *= gg; a1.y *= gg; a1.z *= gg; a1.w *= gg;
      a2.x *= gg; a2.y *= gg; a2.z *= gg; a2.w *= gg;
      a3.x *= gg; a3.y *= gg; a3.z *= gg; a3.w *= gg;
    }
    *(float4*)&R[buf ^ 1][j0 + 0][i0] = a0;
    *(float4*)&R[buf ^ 1][j0 + 1][i0] = a1;
    *(float4*)&R[buf ^ 1][j0 + 2][i0] = a2;
    *(float4*)&R[buf ^ 1][j0 + 3][i0] = a3;
    __syncthreads();
    buf ^= 1;
  }
  float* Ro = qc + (size_t)b * 1024;
#pragma unroll
  for (int m = 0; m < 4; ++m)
    *(float4*)&Ro[(j0 + m) * 32 + i0] = *(const float4*)&R[buf][j0 + m][i0];
}

// ---------------------------------------------------------------------------
// comb1: group product from CGRP chunk matrices (GROUPS waves)
// ---------------------------------------------------------------------------
__global__ __launch_bounds__(64) void k_comb1(const float* __restrict__ qc,
                                              float* __restrict__ r)
{
  const int g = blockIdx.x, lane = threadIdx.x;
  const int j0 = (lane >> 3) * 4, i0 = (lane & 7) * 4;
  __shared__ __align__(16) float R[2][32][36];
  {
    const float* q0 = qc + (size_t)(g * CGRP) * 1024;
#pragma unroll
    for (int m = 0; m < 4; ++m)
      *(float4*)&R[0][j0 + m][i0] = *(const float4*)&q0[(j0 + m) * 32 + i0];
  }
  __syncthreads();
  int buf = 0;
  for (int c = 1; c < CGRP; ++c) {
    const float* ql = qc + (size_t)(g * CGRP + c) * 1024;
    float Qv[4][32];
#pragma unroll
    for (int m = 0; m < 4; ++m)
#pragma unroll
      for (int kk = 0; kk < 8; ++kk) {
        float4 t = *(const float4*)&ql[(j0 + m) * 32 + kk * 4];
        Qv[m][kk * 4 + 0] = t.x; Qv[m][kk * 4 + 1] = t.y;
        Qv[m][kk * 4 + 2] = t.z; Qv[m][kk * 4 + 3] = t.w;
      }
    float4 a0 = {0,0,0,0}, a1 = {0,0,0,0}, a2 = {0,0,0,0}, a3 = {0,0,0,0};
#pragma unroll
    for (int k = 0; k < 32; ++k) {
      float4 rr = *(const float4*)&R[buf][k][i0];
      a0.x += Qv[0][k] * rr.x; a0.y += Qv[0][k] * rr.y; a0.z += Qv[0][k] * rr.z; a0.w += Qv[0][k] * rr.w;
      a1.x += Qv[1][k] * rr.x; a1.y += Qv[1][k] * rr.y; a1.z += Qv[1][k] * rr.z; a1.w += Qv[1][k] * rr.w;
      a2.x += Qv[2][k] * rr.x; a2.y += Qv[2][k] * rr.y; a2.z += Qv[2][k] * rr.z; a2.w += Qv[2][k] * rr.w;
      a3.x += Qv[3][k] * rr.x; a3.y += Qv[3][k] * rr.y; a3.z += Qv[3][k] * rr.z; a3.w += Qv[3][k] * rr.w;
    }
    if (((c & 3) == 3) || c == CGRP - 1) {
      float ps = a0.x + a0.y + a0.z + a0.w + a1.x + a1.y + a1.z + a1.w
               + a2.x + a2.y + a2.z + a2.w + a3.x + a3.y + a3.z + a3.w;
#pragma unroll
      for (int o = 1; o < 64; o <<= 1) ps += __shfl_xor(ps, o);
      float gg = __builtin_amdgcn_rcpf(ps);
      a0.x *= gg; a0.y *= gg; a0.z *= gg; a0.w *= gg;
      a1.x *= gg; a1.y *= gg; a1.z *= gg; a1.w *= gg;
      a2.x *= gg; a2.y *= gg; a2.z *= gg; a2.w *= gg;
      a3.x *= gg; a3.y *= gg; a3.z *= gg; a3.w *= gg;
    }
    *(float4*)&R[buf ^ 1][j0 + 0][i0] = a0;
    *(float4*)&R[buf ^ 1][j0 + 1][i0] = a1;
    *(float4*)&R[buf ^ 1][j0 + 2][i0] = a2;
    *(float4*)&R[buf ^ 1][j0 + 3][i0] = a3;
    __syncthreads();
    buf ^= 1;
  }
  float* Ro = r + (size_t)g * 1024;
#pragma unroll
  for (int m = 0; m < 4; ++m)
    *(float4*)&Ro[(j0 + m) * 32 + i0] = *(const float4*)&R[buf][j0 + m][i0];
}

// ---------------------------------------------------------------------------
// comb2: single wave scans GROUPS group matrices -> group-start states xg.
// Explicit next-iteration prefetch hides the serial global-load latency.
// ---------------------------------------------------------------------------
__global__ __launch_bounds__(64) void k_comb2(const float* __restrict__ pi,
                                              float* __restrict__ ws,
                                              const float* __restrict__ r)
{
  const int lane = threadIdx.x;
  const int j = lane & 31, h = lane >> 5;
  float x = pi[j];
  float4 c0, c1, c2, c3;
  {
    const float4* rv = (const float4*)(r + j * 32 + h * 16);
    c0 = rv[0]; c1 = rv[1]; c2 = rv[2]; c3 = rv[3];
  }
  for (int g = 0; g < GROUPS; ++g) {
    float4 n0 = {0,0,0,0}, n1 = {0,0,0,0}, n2 = {0,0,0,0}, n3 = {0,0,0,0};
    if (g + 1 < GROUPS) {
      const float4* rv = (const float4*)(r + (size_t)(g + 1) * 1024 + j * 32 + h * 16);
      n0 = rv[0]; n1 = rv[1]; n2 = rv[2]; n3 = rv[3];
    }
    if (lane < 32) ws[OFF_XG + g * 32 + j] = x;
    float y = 0.f;
    y += c0.x * __shfl(x, h * 16 + 0);  y += c0.y * __shfl(x, h * 16 + 1);
    y += c0.z * __shfl(x, h * 16 + 2);  y += c0.w * __shfl(x, h * 16 + 3);
    y += c1.x * __shfl(x, h * 16 + 4);  y += c1.y * __shfl(x, h * 16 + 5);
    y += c1.z * __shfl(x, h * 16 + 6);  y += c1.w * __shfl(x, h * 16 + 7);
    y += c2.x * __shfl(x, h * 16 + 8);  y += c2.y * __shfl(x, h * 16 + 9);
    y += c2.z * __shfl(x, h * 16 + 10); y += c2.w * __shfl(x, h * 16 + 11);
    y += c3.x * __shfl(x, h * 16 + 12); y += c3.y * __shfl(x, h * 16 + 13);
    y += c3.z * __shfl(x, h * 16 + 14); y += c3.w * __shfl(x, h * 16 + 15);
    y += __shfl_xor(y, 32);
    float s = y;
#pragma unroll
    for (int o = 1; o < 32; o <<= 1) s += __shfl_xor(s, o);
    x = y * __builtin_amdgcn_rcpf(s);
    c0 = n0; c1 = n1; c2 = n2; c3 = n3;
  }
}

// ---------------------------------------------------------------------------
// comb3: per-group scan of subchunk matrices -> e0 at every subchunk start
// ---------------------------------------------------------------------------
__global__ __launch_bounds__(64) void k_comb3(const float* __restrict__ ws,
                                              const float* __restrict__ qs,
                                              float* __restrict__ e0, int f)
{
  const int g = blockIdx.x, lane = threadIdx.x;
  const int j = lane & 31, h = lane >> 5;
  const int nsub = CGRP * f;
  const size_t base = (size_t)g * nsub;
  float x = ws[OFF_XG + g * 32 + j];
  float4 c0, c1, c2, c3;
  {
    const float4* qv = (const float4*)(qs + base * 1024 + j * 32 + h * 16);
    c0 = qv[0]; c1 = qv[1]; c2 = qv[2]; c3 = qv[3];
  }
  for (int c = 0; c < nsub; ++c) {
    float4 n0 = {0,0,0,0}, n1 = {0,0,0,0}, n2 = {0,0,0,0}, n3 = {0,0,0,0};
    if (c + 1 < nsub) {
      const float4* qv = (const float4*)(qs + (base + c + 1) * 1024 + j * 32 + h * 16);
      n0 = qv[0]; n1 = qv[1]; n2 = qv[2]; n3 = qv[3];
    }
    if (lane < 32) e0[(base + c) * 32 + j] = x;
    float y = 0.f;
    y += c0.x * __shfl(x, h * 16 + 0);  y += c0.y * __shfl(x, h * 16 + 1);
    y += c0.z * __shfl(x, h * 16 + 2);  y += c0.w * __shfl(x, h * 16 + 3);
    y += c1.x * __shfl(x, h * 16 + 4);  y += c1.y * __shfl(x, h * 16 + 5);
    y += c1.z * __shfl(x, h * 16 + 6);  y += c1.w * __shfl(x, h * 16 + 7);
    y += c2.x * __shfl(x, h * 16 + 8);  y += c2.y * __shfl(x, h * 16 + 9);
    y += c2.z * __shfl(x, h * 16 + 10); y += c2.w * __shfl(x, h * 16 + 11);
    y += c3.x * __shfl(x, h * 16 + 12); y += c3.y * __shfl(x, h * 16 + 13);
    y += c3.z * __shfl(x, h * 16 + 14); y += c3.w * __shfl(x, h * 16 + 15);
    y += __shfl_xor(y, 32);
    float s = y;
#pragma unroll
    for (int o = 1; o < 32; o <<= 1) s += __shfl_xor(s, o);
    x = y * __builtin_amdgcn_rcpf(s);
    c0 = n0; c1 = n1; c2 = n2; c3 = n3;
  }
}

// ---------------------------------------------------------------------------
// Phase 2: one wave per subchunk. Half 0: u.W^T x; half 1: u^2.W2^T x.
// loss_t = N2/S; x normalized by 1/S. Bucketized atomics.
// ---------------------------------------------------------------------------
__global__ __launch_bounds__(64) void k_phase2(
    const float* __restrict__ obs2, const float* __restrict__ obs1,
    const float* __restrict__ bate_p, const float* __restrict__ ws,
    const float* __restrict__ e0, float* __restrict__ lossbuf, int slen)
{
  const int b = blockIdx.x, lane = threadIdx.x;
  const int j = lane & 31, h = lane >> 5;
  __shared__ float cts[100];
  __shared__ __align__(16) float xs[2][32];
  const int t0 = b * slen;
  {
    float bate = bate_p[0];
    for (int l = lane; l < slen; l += 64)
      cts[l] = obs2[t0 + l] - bate * obs1[t0 + l];
  }
  float Wc[32];
  const float* Wsel = ws + (h ? OFF_W2 : OFF_W);
#pragma unroll
  for (int k = 0; k < 32; ++k) Wc[k] = Wsel[k * 32 + j];
  const float i2vl = ws[OFF_I2V + j];
  if (lane < 32) xs[0][j] = e0[(size_t)b * 32 + j];
  __syncthreads();

  float lossacc = 0.f;
  int buf = 0;
  for (int s = 0; s < slen; ++s) {
    float ct = cts[s];
    float u  = exp2f(-ct * i2vl);
    float xk[32];
    const float4* xv = (const float4*)xs[buf];
#pragma unroll
    for (int k8 = 0; k8 < 8; ++k8) {
      float4 q = xv[k8];
      xk[k8 * 4 + 0] = q.x; xk[k8 * 4 + 1] = q.y;
      xk[k8 * 4 + 2] = q.z; xk[k8 * 4 + 3] = q.w;
    }
    float dot = 0.f;
#pragma unroll
    for (int k = 0; k < 32; ++k) dot += Wc[k] * xk[k];
    float numj = u * dot;                 // meaningful on half 0
    float red  = h ? (u * u * dot) : numj;
#pragma unroll
    for (int o = 1; o < 32; o <<= 1) red += __shfl_xor(red, o);
    float cross = __shfl_xor(red, 32);
    float S  = h ? cross : red;
    float N2 = h ? red   : cross;
    float rs = __builtin_amdgcn_rcpf(S);
    lossacc += N2 * rs;
    if (lane < 32) xs[buf ^ 1][j] = numj * rs;
    __syncthreads();
    buf ^= 1;
  }
  if (lane == 0) atomicAdd(&lossbuf[b & 63], lossacc);
}

__global__ __launch_bounds__(64) void k_finish(const float* __restrict__ lossbuf,
                                               float* __restrict__ out)
{
  float v = lossbuf[threadIdx.x];
#pragma unroll
  for (int o = 1; o < 64; o <<= 1) v += __shfl_xor(v, o);
  if (threadIdx.x == 0) out[0] = v;
}

extern "C" void kernel_launch(void* const* d_in, const int* in_sizes, int n_in,
                              void* d_out, int out_size, void* d_ws, size_t ws_size,
                              hipStream_t stream)
{
  (void)in_sizes; (void)n_in;
  const float* obs2 = (const float*)d_in[0];
  const float* obs1 = (const float*)d_in[1];
  const float* mean = (const float*)d_in[2];
  const float* var  = (const float*)d_in[3];
  const float* bate = (const float*)d_in[4];
  const float* pi   = (const float*)d_in[5];
  const float* aij  = (const float*)d_in[6];
  float* ws  = (float*)d_ws;
  float* out = (float*)d_out;

  // pick subchunk factor F by available workspace (constant across calls)
  size_t wsf = ws_size / sizeof(float);
  auto need = [](int F) -> size_t {
    return OFF_QS + (size_t)F * CHUNKS * 1024 + (F > 1 ? (size_t)CHUNKS * 1024 : 0)
         + (size_t)GROUPS * 1024 + (size_t)F * CHUNKS * 32;
  };
  int F = (wsf >= need(4)) ? 4 : (wsf >= need(2)) ? 2 : 1;
  const int SUB = CHUNKS * F, slen = TN / SUB;

  float* qs = ws + OFF_QS;
  float* qc = (F > 1) ? qs + (size_t)SUB * 1024 : qs;
  float* r  = qc + (size_t)CHUNKS * 1024;
  float* e0 = r  + (size_t)GROUPS * 1024;
  float* lb = ws + OFF_LB;

  hipMemsetAsync(out, 0, sizeof(float) * out_size, stream);
  hipMemsetAsync((void*)lb, 0, 64 * sizeof(float), stream);
  k_prep  <<<1,      256, 0, stream>>>(mean, var, bate, aij, ws);
  k_phase1<<<SUB,     64, 0, stream>>>(obs2, obs1, bate, ws, qs, slen);
  if (F > 1)
    k_comb0<<<CHUNKS, 64, 0, stream>>>(qs, qc, F);
  k_comb1 <<<GROUPS,  64, 0, stream>>>(qc, r);
  k_comb2 <<<1,       64, 0, stream>>>(pi, ws, r);
  k_comb3 <<<GROUPS,  64, 0, stream>>>(ws, qs, e0, F);
  k_phase2<<<SUB,     64, 0, stream>>>(obs2, obs1, bate, ws, e0, lb, slen);
  k_finish<<<1,       64, 0, stream>>>(lb, out);
}